// Round 1
// baseline (603.711 us; speedup 1.0000x reference)
//
#include <hip/hip_runtime.h>
#include <hip/hip_bf16.h>

// Problem constants
#define DD   256
#define DD3  768
#define NB   128
#define NE   7      // 1 pos_u + 1 pos_v + 5 neg embeddings

// Workspace layout (float offsets)
#define OFF_TVT  0u          // tv transposed [256 i][128 b]
#define OFF_TVB  32768u      // tvB [128 b][256 j]
#define OFF_EMB  65536u      // emb [7 e][128 b][768 k]
#define OFF_H3   753664u     // h3  [128 b][7 e][256 j]
#define OFF_G    983040u     // G = W4^T W4 [256][256]
#define OFF_GV   1048576u    // g = W4^T b4 [256]
#define OFF_SC   1048832u    // score per b [128]
#define OFF_NS   1048960u    // neg score per b [128]

// ---------------------------------------------------------------------------
// Kernel A: h1 = tanh(t/20 * m1 + b1); tv = tanh(h1 @ W2^T + b2); tvB = tv @ B
// grid 128 (b), block 256 (i)
__global__ void k_setup(const float* __restrict__ timev,
                        const float* __restrict__ m1,
                        const float* __restrict__ b1,
                        const float* __restrict__ W2,
                        const float* __restrict__ b2,
                        const float* __restrict__ Bm,
                        float* __restrict__ tv_t,
                        float* __restrict__ tvB) {
  const int b = blockIdx.x, i = threadIdx.x;
  __shared__ float h1[DD];
  __shared__ float tvs[DD];
  const float t = timev[b] * (1.0f / 20.0f);
  h1[i] = tanhf(fmaf(t, m1[i], b1[i]));
  __syncthreads();
  float acc = b2[i];
  const float* w2r = W2 + i * DD;
#pragma unroll 8
  for (int jj = 0; jj < DD; ++jj) acc = fmaf(h1[jj], w2r[jj], acc);
  const float tvi = tanhf(acc);
  tvs[i] = tvi;
  tv_t[i * NB + b] = tvi;   // transposed for main kernel
  __syncthreads();
  float a2 = 0.f;
#pragma unroll 8
  for (int ii = 0; ii < DD; ++ii) a2 = fmaf(tvs[ii], Bm[ii * DD + i], a2);
  tvB[b * DD + i] = a2;
}

// ---------------------------------------------------------------------------
// Kernel B: gather embeddings -> emb[e][b][k]
// grid 896 (b*7+e), block 192 (float4 per thread)
__global__ void k_gather(const int* __restrict__ pos_u,
                         const int* __restrict__ pos_v,
                         const int* __restrict__ neg_v,
                         const float* __restrict__ U,
                         const float* __restrict__ V,
                         float* __restrict__ emb) {
  const int be = blockIdx.x;
  const int b = be / NE, e = be % NE;
  const float* src;
  if (e == 0)      src = U + (long)pos_u[b] * DD3;
  else if (e == 1) src = V + (long)pos_v[b] * DD3;
  else             src = V + (long)neg_v[b * 5 + (e - 2)] * DD3;
  const float4 v = ((const float4*)src)[threadIdx.x];
  ((float4*)(emb + ((long)e * NB + b) * DD3))[threadIdx.x] = v;
}

// ---------------------------------------------------------------------------
// Kernel G: G = W4^T W4 (256x256), g = W4^T b4
// grid 256 (p), block 1024: q = t&255, n-slice = t>>8 (4 slices of 192)
__global__ __launch_bounds__(1024) void k_gram(const float* __restrict__ W4,
                                               const float* __restrict__ b4,
                                               float* __restrict__ G,
                                               float* __restrict__ gv) {
  const int p = blockIdx.x, t = threadIdx.x;
  const int q = t & 255, nq = t >> 8;
  __shared__ float colp[DD3];
  __shared__ float red[4][257];
  __shared__ float gred[4];
  for (int n = t; n < DD3; n += 1024) colp[n] = W4[n * DD + p];
  __syncthreads();
  float acc = 0.f;
  const int n0 = nq * 192;
#pragma unroll 8
  for (int n = n0; n < n0 + 192; ++n) acc = fmaf(colp[n], W4[n * DD + q], acc);
  red[nq][q] = acc;
  float gp = 0.f;
  for (int n = n0; n < n0 + 192; ++n) gp = fmaf(b4[n], colp[n], gp);
  if (q == 0) gred[nq] = gp;
  __syncthreads();
  if (t < 256) G[p * DD + t] = red[0][t] + red[1][t] + red[2][t] + red[3][t];
  if (t == 0) gv[p] = gred[0] + gred[1] + gred[2] + gred[3];
}

// ---------------------------------------------------------------------------
// Kernel C (main): per block j: M[b,k] = sum_i tv[b,i]*T[i,j,k],
// h3[b,e,j] = sum_k M[b,k]*emb[e,b,k] + tvB[b,j]
// grid 256 (j), block 512. Thread tile: 4 b x 4 k. K processed in 12 chunks of 64.
__global__ __launch_bounds__(512) void k_main(const float* __restrict__ T,
                                              const float* __restrict__ tv_t,
                                              const float* __restrict__ emb,
                                              const float* __restrict__ tvB,
                                              float* __restrict__ h3) {
  __shared__ float T_s[32 * 64];           // [32 i][64 k] tile, 8 KB
  const int t = threadIdx.x;
  const int j = blockIdx.x;
  const int kq = t & 15;                   // k-quad index (k4 = kq*4)
  const int bq = t >> 4;                   // b-quad index (b4 = bq*4), 0..31

  float prt[NE][4];
#pragma unroll
  for (int e = 0; e < NE; ++e)
#pragma unroll
    for (int x = 0; x < 4; ++x) prt[e][x] = 0.f;

  auto ldT = [&](int s) -> float4 {
    const int it = s & 7, cc = s >> 3;
    return *(const float4*)(T + (((long)(it * 32 + bq) * DD + j) * DD3 + cc * 64 + kq * 4));
  };
  float4 tnext = ldT(0);

  for (int c = 0; c < 12; ++c) {
    float M[4][4];
#pragma unroll
    for (int x = 0; x < 4; ++x)
#pragma unroll
      for (int y = 0; y < 4; ++y) M[x][y] = 0.f;

    for (int it = 0; it < 8; ++it) {
      __syncthreads();                       // prior readers of T_s done
      ((float4*)T_s)[bq * 16 + kq] = tnext;  // lane-linear store, conflict-free
      const int sn = c * 8 + it + 1;
      if (sn < 96) tnext = ldT(sn);          // prefetch next tile
      __syncthreads();
      const float* tvrow = tv_t + (it * 32) * NB + bq * 4;
#pragma unroll 8
      for (int ii = 0; ii < 32; ++ii) {
        const float4 tvv = *(const float4*)(tvrow + ii * NB);      // broadcast to 16 lanes
        const float4 tt  = *(const float4*)(T_s + ii * 64 + kq * 4);
        M[0][0] = fmaf(tvv.x, tt.x, M[0][0]);
        M[0][1] = fmaf(tvv.x, tt.y, M[0][1]);
        M[0][2] = fmaf(tvv.x, tt.z, M[0][2]);
        M[0][3] = fmaf(tvv.x, tt.w, M[0][3]);
        M[1][0] = fmaf(tvv.y, tt.x, M[1][0]);
        M[1][1] = fmaf(tvv.y, tt.y, M[1][1]);
        M[1][2] = fmaf(tvv.y, tt.z, M[1][2]);
        M[1][3] = fmaf(tvv.y, tt.w, M[1][3]);
        M[2][0] = fmaf(tvv.z, tt.x, M[2][0]);
        M[2][1] = fmaf(tvv.z, tt.y, M[2][1]);
        M[2][2] = fmaf(tvv.z, tt.z, M[2][2]);
        M[2][3] = fmaf(tvv.z, tt.w, M[2][3]);
        M[3][0] = fmaf(tvv.w, tt.x, M[3][0]);
        M[3][1] = fmaf(tvv.w, tt.y, M[3][1]);
        M[3][2] = fmaf(tvv.w, tt.z, M[3][2]);
        M[3][3] = fmaf(tvv.w, tt.w, M[3][3]);
      }
    }
    // fuse: contract this k-chunk of M with embeddings, accumulate in registers
    const int kb = c * 64 + kq * 4;
#pragma unroll
    for (int e = 0; e < NE; ++e) {
#pragma unroll
      for (int x = 0; x < 4; ++x) {
        const float4 em = *(const float4*)(emb + ((long)(e * NB + bq * 4 + x)) * DD3 + kb);
        prt[e][x] = fmaf(M[x][0], em.x, prt[e][x]);
        prt[e][x] = fmaf(M[x][1], em.y, prt[e][x]);
        prt[e][x] = fmaf(M[x][2], em.z, prt[e][x]);
        prt[e][x] = fmaf(M[x][3], em.w, prt[e][x]);
      }
    }
  }
  // reduce partials across the 16 kq lanes of each 16-lane group
#pragma unroll
  for (int e = 0; e < NE; ++e) {
#pragma unroll
    for (int x = 0; x < 4; ++x) {
      float v = prt[e][x];
      v += __shfl_xor(v, 1);
      v += __shfl_xor(v, 2);
      v += __shfl_xor(v, 4);
      v += __shfl_xor(v, 8);
      if (kq == 0) {
        const int b = bq * 4 + x;
        h3[((long)b * NE + e) * DD + j] = v + tvB[b * DD + j];
      }
    }
  }
}

// ---------------------------------------------------------------------------
// Kernel D: scores per b via Gram trick.
// use_w . use_c_e = h3_u^T G h3_e + g.h3_u + g.h3_e + b4.b4
// grid 128 (b), block 256
__global__ void k_score(const float* __restrict__ h3,
                        const float* __restrict__ G,
                        const float* __restrict__ gv,
                        const float* __restrict__ b4,
                        float* __restrict__ scoreb,
                        float* __restrict__ negb) {
  const int b = blockIdx.x, t = threadIdx.x;
  __shared__ float h3s[NE * DD];
  __shared__ float red[4][16];
  for (int idx = t; idx < NE * DD; idx += 256) h3s[idx] = h3[(long)b * NE * DD + idx];
  __syncthreads();
  // r[t] = sum_jp G[jp][t] * h3_u[jp]   (= (W4^T W4 h3_u)[t], exact w/o symmetry)
  float racc = 0.f;
#pragma unroll 8
  for (int jp = 0; jp < DD; ++jp) racc = fmaf(G[jp * DD + t], h3s[jp], racc);

  float loc[14];
#pragma unroll
  for (int e = 1; e < NE; ++e) loc[e - 1] = racc * h3s[e * DD + t];       // d_e partials
  loc[6] = gv[t] * h3s[t];                                                // g . h3_u
#pragma unroll
  for (int e = 1; e < NE; ++e) loc[6 + e] = gv[t] * h3s[e * DD + t];      // g . h3_e
  loc[13] = b4[t] * b4[t] + b4[t + 256] * b4[t + 256] + b4[t + 512] * b4[t + 512];

  const int lane = t & 63, wid = t >> 6;
#pragma unroll
  for (int qd = 0; qd < 14; ++qd) {
    float v = loc[qd];
#pragma unroll
    for (int m = 1; m < 64; m <<= 1) v += __shfl_xor(v, m);
    if (lane == 0) red[wid][qd] = v;
  }
  __syncthreads();
  if (t == 0) {
    float r[14];
#pragma unroll
    for (int qd = 0; qd < 14; ++qd)
      r[qd] = red[0][qd] + red[1][qd] + red[2][qd] + red[3][qd];
    const float c = r[13], gu = r[6];
    auto logsig = [](float x) { return fminf(x, 0.f) - log1pf(expf(-fabsf(x))); };
    float dv = r[0] + gu + r[7] + c;
    dv = fminf(fmaxf(dv, -10.f), 10.f);
    const float sc = -logsig(dv);
    float ns = 0.f;
    for (int l = 1; l < 6; ++l) {
      float dn = r[l] + gu + r[7 + l] + c;
      dn = fminf(fmaxf(dn, -10.f), 10.f);
      ns -= logsig(-dn);
    }
    scoreb[b] = sc;
    negb[b] = ns * 0.2f;
  }
}

// ---------------------------------------------------------------------------
// Kernel E: final means. 1 block, 128 threads.
__global__ void k_final(const float* __restrict__ scoreb,
                        const float* __restrict__ negb,
                        float* __restrict__ out) {
  const int t = threadIdx.x;
  float s = scoreb[t], n = negb[t];
#pragma unroll
  for (int m = 1; m < 64; m <<= 1) {
    s += __shfl_xor(s, m);
    n += __shfl_xor(n, m);
  }
  __shared__ float rs[2], rn[2];
  if ((t & 63) == 0) { rs[t >> 6] = s; rn[t >> 6] = n; }
  __syncthreads();
  if (t == 0) {
    const float S = (rs[0] + rs[1]) * (1.0f / 128.0f);
    const float N = (rn[0] + rn[1]) * (1.0f / 128.0f);
    out[0] = S + N;
    out[1] = S;
    out[2] = N;
  }
}

// ---------------------------------------------------------------------------
extern "C" void kernel_launch(void* const* d_in, const int* in_sizes, int n_in,
                              void* d_out, int out_size, void* d_ws, size_t ws_size,
                              hipStream_t stream) {
  const int*   pos_u = (const int*)d_in[0];
  const int*   pos_v = (const int*)d_in[1];
  const int*   neg_v = (const int*)d_in[2];
  const float* timev = (const float*)d_in[3];
  const float* m1    = (const float*)d_in[4];
  const float* b1    = (const float*)d_in[5];
  const float* W2    = (const float*)d_in[6];
  const float* b2    = (const float*)d_in[7];
  const float* W4    = (const float*)d_in[8];
  const float* b4    = (const float*)d_in[9];
  const float* U     = (const float*)d_in[10];
  const float* V     = (const float*)d_in[11];
  const float* T     = (const float*)d_in[12];
  const float* Bm    = (const float*)d_in[13];

  float* ws     = (float*)d_ws;
  float* tv_t   = ws + OFF_TVT;
  float* tvB    = ws + OFF_TVB;
  float* emb    = ws + OFF_EMB;
  float* h3     = ws + OFF_H3;
  float* G      = ws + OFF_G;
  float* gv     = ws + OFF_GV;
  float* scoreb = ws + OFF_SC;
  float* negb   = ws + OFF_NS;
  float* out    = (float*)d_out;

  k_setup<<<128, 256, 0, stream>>>(timev, m1, b1, W2, b2, Bm, tv_t, tvB);
  k_gather<<<896, 192, 0, stream>>>(pos_u, pos_v, neg_v, U, V, emb);
  k_gram<<<256, 1024, 0, stream>>>(W4, b4, G, gv);
  k_main<<<256, 512, 0, stream>>>(T, tv_t, emb, tvB, h3);
  k_score<<<128, 256, 0, stream>>>(h3, G, gv, b4, scoreb, negb);
  k_final<<<1, 128, 0, stream>>>(scoreb, negb, out);
}

// Round 2
// 182.510 us; speedup vs baseline: 3.3078x; 3.3078x over previous
//
#include <hip/hip_runtime.h>
#include <hip/hip_bf16.h>

// Problem constants
#define DD   256
#define DD3  768
#define NB   128
#define NE   7      // 1 pos_u + 1 pos_v + 5 neg embeddings

// Workspace layout (float offsets)
#define OFF_TVT  0u          // tv transposed [256 i][128 b]
#define OFF_TVB  32768u      // tvB [128 b][256 j]
#define OFF_EMB  65536u      // emb [7 e][128 b][768 k] fp32
#define OFF_H3   753664u     // h3  [128 b][7 e][256 j]
#define OFF_G    983040u     // G = W4^T W4 [256][256]
#define OFF_GV   1048576u    // g = W4^T b4 [256]
#define OFF_SC   1048832u    // tvf (bf16 frags, 16384 floats) ALIASED with scoreb/negb:
                             // k_pack writes tvf -> k_main reads -> k_score overwrites head
                             // with scoreb/negb (tvf dead by then); next call re-packs.

typedef __attribute__((ext_vector_type(8))) short bf16x8;
typedef __attribute__((ext_vector_type(4))) float f32x4;

__device__ __forceinline__ unsigned bf16rne(float f) {
  unsigned u = __float_as_uint(f);
  return (u + 0x7fffu + ((u >> 16) & 1u)) >> 16;   // round-to-nearest-even
}

__device__ __forceinline__ void gld16(const float* g, float* l) {
  // async global->LDS, 16B per lane; LDS dest = wave-uniform base + lane*16
  __builtin_amdgcn_global_load_lds(
      (const __attribute__((address_space(1))) unsigned int*)g,
      (__attribute__((address_space(3))) unsigned int*)l, 16, 0, 0);
}

// ---------------------------------------------------------------------------
// Kernel A: h1 = tanh(t/20 * m1 + b1); tv = tanh(h1 @ W2^T + b2); tvB = tv @ B
__global__ void k_setup(const float* __restrict__ timev,
                        const float* __restrict__ m1,
                        const float* __restrict__ b1,
                        const float* __restrict__ W2,
                        const float* __restrict__ b2,
                        const float* __restrict__ Bm,
                        float* __restrict__ tv_t,
                        float* __restrict__ tvB) {
  const int b = blockIdx.x, i = threadIdx.x;
  __shared__ float h1[DD];
  __shared__ float tvs[DD];
  const float t = timev[b] * (1.0f / 20.0f);
  h1[i] = tanhf(fmaf(t, m1[i], b1[i]));
  __syncthreads();
  float acc = b2[i];
  const float* w2r = W2 + i * DD;
#pragma unroll 8
  for (int jj = 0; jj < DD; ++jj) acc = fmaf(h1[jj], w2r[jj], acc);
  const float tvi = tanhf(acc);
  tvs[i] = tvi;
  tv_t[i * NB + b] = tvi;
  __syncthreads();
  float a2 = 0.f;
#pragma unroll 8
  for (int ii = 0; ii < DD; ++ii) a2 = fmaf(tvs[ii], Bm[ii * DD + i], a2);
  tvB[b * DD + i] = a2;
}

// ---------------------------------------------------------------------------
// Pack tv into bf16 MFMA B-fragments: frag f = bf*8+it (bf=global b-frag 0..7),
// lane l: elem jj = tv[b = bf*16 + (l&15)][i = it*32 + ((l>>4)&3)*8 + jj]
__global__ void k_pack(const float* __restrict__ tv_t, short* __restrict__ tvf) {
  const int t = blockIdx.x * 256 + threadIdx.x;   // 4096 threads
  const int f = t >> 6, l = t & 63;
  const int b = (f >> 3) * 16 + (l & 15);
  const int i0 = (f & 7) * 32 + ((l >> 4) & 3) * 8;
  bf16x8 v;
#pragma unroll
  for (int jj = 0; jj < 8; ++jj)
    v[jj] = (short)bf16rne(tv_t[(i0 + jj) * NB + b]);
  *(bf16x8*)(tvf + (long)t * 8) = v;
}

// ---------------------------------------------------------------------------
// Kernel B: gather embeddings -> emb[e][b][k] fp32
__global__ void k_gather(const int* __restrict__ pos_u,
                         const int* __restrict__ pos_v,
                         const int* __restrict__ neg_v,
                         const float* __restrict__ U,
                         const float* __restrict__ V,
                         float* __restrict__ emb) {
  const int be = blockIdx.x;
  const int b = be / NE, e = be % NE;
  const float* src;
  if (e == 0)      src = U + (long)pos_u[b] * DD3;
  else if (e == 1) src = V + (long)pos_v[b] * DD3;
  else             src = V + (long)neg_v[b * 5 + (e - 2)] * DD3;
  const float4 v = ((const float4*)src)[threadIdx.x];
  ((float4*)(emb + ((long)e * NB + b) * DD3))[threadIdx.x] = v;
}

// ---------------------------------------------------------------------------
// Kernel G: G = W4^T W4 (256x256), g = W4^T b4
__global__ __launch_bounds__(1024) void k_gram(const float* __restrict__ W4,
                                               const float* __restrict__ b4,
                                               float* __restrict__ G,
                                               float* __restrict__ gv) {
  const int p = blockIdx.x, t = threadIdx.x;
  const int q = t & 255, nq = t >> 8;
  __shared__ float colp[DD3];
  __shared__ float red[4][257];
  __shared__ float gred[4];
  for (int n = t; n < DD3; n += 1024) colp[n] = W4[n * DD + p];
  __syncthreads();
  float acc = 0.f;
  const int n0 = nq * 192;
#pragma unroll 8
  for (int n = n0; n < n0 + 192; ++n) acc = fmaf(colp[n], W4[n * DD + q], acc);
  red[nq][q] = acc;
  float gp = 0.f;
  for (int n = n0; n < n0 + 192; ++n) gp = fmaf(b4[n], colp[n], gp);
  if (q == 0) gred[nq] = gp;
  __syncthreads();
  if (t < 256) G[p * DD + t] = red[0][t] + red[1][t] + red[2][t] + red[3][t];
  if (t == 0) gv[p] = gred[0] + gred[1] + gred[2] + gred[3];
}

// ---------------------------------------------------------------------------
// Main kernel: per block j. MFMA computes D[m=k, n=b] = sum_i T[i,j,k]*tv[b,i]
// (bf16 inputs, fp32 acc). T staged fp32 via global_load_lds (double-buffered,
// counted vmcnt, raw s_barrier), converted to bf16 in registers.
// Epilogue fuses h3[b,e,j] = sum_k D[k,b]*emb[e,b,k] (+tvB) per 128-k chunk.
// Geometry: 512 thr = 8 waves; wave = (bq = w>>1: 32 b) x (mh = w&1: 64 k).
// Per kc (128 k): acc frags [mf=4 k-frags][nf=2 b-frags], K-steps it=0..7 (i).
// LDS tile per stage (kc,it): [32 i][128 k] fp32, XOR-swizzled k ^= ((i>>3)&3)<<4
// on BOTH global source and LDS read -> 2-way bank conflicts (free).
__global__ __launch_bounds__(512) void k_main(const float* __restrict__ T,
                                              const short* __restrict__ tvf,
                                              const float* __restrict__ emb,
                                              const float* __restrict__ tvB,
                                              float* __restrict__ h3) {
  __shared__ float Ts[2][4096];      // 2 x 16 KB
  __shared__ float h3red[NB][NE];
  const int t = threadIdx.x;
  const int j = blockIdx.x;
  const int l = t & 63;
  const int w = t >> 6;
  const int bq = w >> 1;             // b-quarter (n side)
  const int mh = w & 1;              // k-half within 128-k chunk (m side)
  const int l15 = l & 15;
  const int l4 = (l >> 4) & 3;
  const int lhi = l >> 5;
  const int kb = (l & 31) * 4;

  // Preload tv B-fragments [nf][it] (bf16, packed by k_pack)
  bf16x8 tvfr[2][8];
#pragma unroll
  for (int nf = 0; nf < 2; ++nf)
#pragma unroll
    for (int it = 0; it < 8; ++it)
      tvfr[nf][it] = *(const bf16x8*)(tvf + ((((bq * 2 + nf) * 8) + it) * 64 + l) * 8);

  // Pre-swizzled per-lane global staging pointers (q=0,1 -> i_loc offset +0/+2)
  const int i0 = 4 * w + lhi, i1 = i0 + 2;
  const float* gp0 = T + (long)i0 * 196608 + j * 768 + (kb ^ (((i0 >> 3) & 3) << 4));
  const float* gp1 = T + (long)i1 * 196608 + j * 768 + (kb ^ (((i1 >> 3) & 3) << 4));

  auto stage = [&](int kcp, int itp, int bufp) {
    const long o = (long)itp * 6291456 + kcp * 128;
    gld16(gp0 + o, &Ts[bufp][(w * 2 + 0) * 256]);
    gld16(gp1 + o, &Ts[bufp][(w * 2 + 1) * 256]);
  };

  float h3p[NE][2];
#pragma unroll
  for (int e = 0; e < NE; ++e) { h3p[e][0] = 0.f; h3p[e][1] = 0.f; }

  stage(0, 0, 0);
  const int kcol0 = mh * 64;

#pragma unroll 1
  for (int kc = 0; kc < 6; ++kc) {
    f32x4 acc[4][2];
#pragma unroll
    for (int mf = 0; mf < 4; ++mf) {
      acc[mf][0] = {0.f, 0.f, 0.f, 0.f};
      acc[mf][1] = {0.f, 0.f, 0.f, 0.f};
    }
#pragma unroll
    for (int it = 0; it < 8; ++it) {
      if (it < 7) {
        stage(kc, it + 1, (it + 1) & 1);
        asm volatile("s_waitcnt vmcnt(2)" ::: "memory");
      } else if (kc < 5) {
        stage(kc + 1, 0, 0);
        asm volatile("s_waitcnt vmcnt(2)" ::: "memory");
      } else {
        asm volatile("s_waitcnt vmcnt(0)" ::: "memory");
      }
      __builtin_amdgcn_s_barrier();
      asm volatile("" ::: "memory");
      const float* tsb = &Ts[it & 1][0];
#pragma unroll
      for (int mf = 0; mf < 4; ++mf) {
        const int kx = (kcol0 + mf * 16 + l15) ^ (l4 << 4);
        bf16x8 af;
#pragma unroll
        for (int jj = 0; jj < 8; ++jj)
          af[jj] = (short)bf16rne(tsb[(l4 * 8 + jj) * 128 + kx]);
        acc[mf][0] = __builtin_amdgcn_mfma_f32_16x16x32_bf16(af, tvfr[0][it], acc[mf][0], 0, 0, 0);
        acc[mf][1] = __builtin_amdgcn_mfma_f32_16x16x32_bf16(af, tvfr[1][it], acc[mf][1], 0, 0, 0);
      }
      asm volatile("" ::: "memory");
      __builtin_amdgcn_s_barrier();
      asm volatile("" ::: "memory");
    }
    // Epilogue for this 128-k chunk: h3p[e][nf] += dot(acc, emb) over lane's 4 k
    // (D rows m = l4*4 + r are 4 CONSECUTIVE k -> float4 emb loads)
#pragma unroll
    for (int nf = 0; nf < 2; ++nf) {
      const int b = bq * 32 + nf * 16 + l15;
#pragma unroll
      for (int mf = 0; mf < 4; ++mf) {
        const long ko = (long)kc * 128 + mh * 64 + mf * 16 + l4 * 4;
#pragma unroll
        for (int e = 0; e < NE; ++e) {
          const f32x4 em = *(const f32x4*)(emb + ((long)e * NB + b) * 768 + ko);
          float s = h3p[e][nf];
          s = fmaf(acc[mf][nf][0], em[0], s);
          s = fmaf(acc[mf][nf][1], em[1], s);
          s = fmaf(acc[mf][nf][2], em[2], s);
          s = fmaf(acc[mf][nf][3], em[3], s);
          h3p[e][nf] = s;
        }
      }
    }
  }

  // Reduce partials over the 4 lane-quads (l>>4) holding different k rows
  float hr[NE][2];
#pragma unroll
  for (int e = 0; e < NE; ++e)
#pragma unroll
    for (int nf = 0; nf < 2; ++nf) {
      float v = h3p[e][nf];
      v += __shfl_xor(v, 16);
      v += __shfl_xor(v, 32);
      hr[e][nf] = v;
    }
  __syncthreads();
  if (mh == 0 && l < 16) {
#pragma unroll
    for (int e = 0; e < NE; ++e) {
      h3red[bq * 32 + l][e]      = hr[e][0];
      h3red[bq * 32 + 16 + l][e] = hr[e][1];
    }
  }
  __syncthreads();
  if (mh == 1 && l < 16) {
#pragma unroll
    for (int nf = 0; nf < 2; ++nf) {
      const int b = bq * 32 + nf * 16 + l;
      const float tb = tvB[b * DD + j];
#pragma unroll
      for (int e = 0; e < NE; ++e)
        h3[((long)b * NE + e) * DD + j] = h3red[b][e] + hr[e][nf] + tb;
    }
  }
}

// ---------------------------------------------------------------------------
// Kernel D: scores per b via Gram trick.
__global__ void k_score(const float* __restrict__ h3,
                        const float* __restrict__ G,
                        const float* __restrict__ gv,
                        const float* __restrict__ b4,
                        float* __restrict__ scoreb,
                        float* __restrict__ negb) {
  const int b = blockIdx.x, t = threadIdx.x;
  __shared__ float h3s[NE * DD];
  __shared__ float red[4][16];
  for (int idx = t; idx < NE * DD; idx += 256) h3s[idx] = h3[(long)b * NE * DD + idx];
  __syncthreads();
  float racc = 0.f;
#pragma unroll 8
  for (int jp = 0; jp < DD; ++jp) racc = fmaf(G[jp * DD + t], h3s[jp], racc);

  float loc[14];
#pragma unroll
  for (int e = 1; e < NE; ++e) loc[e - 1] = racc * h3s[e * DD + t];
  loc[6] = gv[t] * h3s[t];
#pragma unroll
  for (int e = 1; e < NE; ++e) loc[6 + e] = gv[t] * h3s[e * DD + t];
  loc[13] = b4[t] * b4[t] + b4[t + 256] * b4[t + 256] + b4[t + 512] * b4[t + 512];

  const int lane = t & 63, wid = t >> 6;
#pragma unroll
  for (int qd = 0; qd < 14; ++qd) {
    float v = loc[qd];
#pragma unroll
    for (int m = 1; m < 64; m <<= 1) v += __shfl_xor(v, m);
    if (lane == 0) red[wid][qd] = v;
  }
  __syncthreads();
  if (t == 0) {
    float r[14];
#pragma unroll
    for (int qd = 0; qd < 14; ++qd)
      r[qd] = red[0][qd] + red[1][qd] + red[2][qd] + red[3][qd];
    const float c = r[13], gu = r[6];
    auto logsig = [](float x) { return fminf(x, 0.f) - log1pf(expf(-fabsf(x))); };
    float dv = r[0] + gu + r[7] + c;
    dv = fminf(fmaxf(dv, -10.f), 10.f);
    const float sc = -logsig(dv);
    float ns = 0.f;
    for (int lx = 1; lx < 6; ++lx) {
      float dn = r[lx] + gu + r[7 + lx] + c;
      dn = fminf(fmaxf(dn, -10.f), 10.f);
      ns -= logsig(-dn);
    }
    scoreb[b] = sc;
    negb[b] = ns * 0.2f;
  }
}

// ---------------------------------------------------------------------------
__global__ void k_final(const float* __restrict__ scoreb,
                        const float* __restrict__ negb,
                        float* __restrict__ out) {
  const int t = threadIdx.x;
  float s = scoreb[t], n = negb[t];
#pragma unroll
  for (int m = 1; m < 64; m <<= 1) {
    s += __shfl_xor(s, m);
    n += __shfl_xor(n, m);
  }
  __shared__ float rs[2], rn[2];
  if ((t & 63) == 0) { rs[t >> 6] = s; rn[t >> 6] = n; }
  __syncthreads();
  if (t == 0) {
    const float S = (rs[0] + rs[1]) * (1.0f / 128.0f);
    const float N = (rn[0] + rn[1]) * (1.0f / 128.0f);
    out[0] = S + N;
    out[1] = S;
    out[2] = N;
  }
}

// ---------------------------------------------------------------------------
extern "C" void kernel_launch(void* const* d_in, const int* in_sizes, int n_in,
                              void* d_out, int out_size, void* d_ws, size_t ws_size,
                              hipStream_t stream) {
  const int*   pos_u = (const int*)d_in[0];
  const int*   pos_v = (const int*)d_in[1];
  const int*   neg_v = (const int*)d_in[2];
  const float* timev = (const float*)d_in[3];
  const float* m1    = (const float*)d_in[4];
  const float* b1    = (const float*)d_in[5];
  const float* W2    = (const float*)d_in[6];
  const float* b2    = (const float*)d_in[7];
  const float* W4    = (const float*)d_in[8];
  const float* b4    = (const float*)d_in[9];
  const float* U     = (const float*)d_in[10];
  const float* V     = (const float*)d_in[11];
  const float* T     = (const float*)d_in[12];
  const float* Bm    = (const float*)d_in[13];

  float* ws     = (float*)d_ws;
  float* tv_t   = ws + OFF_TVT;
  float* tvB    = ws + OFF_TVB;
  float* emb    = ws + OFF_EMB;
  float* h3     = ws + OFF_H3;
  float* G      = ws + OFF_G;
  float* gv     = ws + OFF_GV;
  short* tvf    = (short*)(ws + OFF_SC);   // aliased: dead before k_score writes
  float* scoreb = ws + OFF_SC;
  float* negb   = ws + OFF_SC + 128;
  float* out    = (float*)d_out;

  k_setup<<<128, 256, 0, stream>>>(timev, m1, b1, W2, b2, Bm, tv_t, tvB);
  k_pack<<<16, 256, 0, stream>>>(tv_t, tvf);
  k_gather<<<896, 192, 0, stream>>>(pos_u, pos_v, neg_v, U, V, emb);
  k_gram<<<256, 1024, 0, stream>>>(W4, b4, G, gv);
  k_main<<<256, 512, 0, stream>>>(T, tvf, emb, tvB, h3);
  k_score<<<128, 256, 0, stream>>>(h3, G, gv, b4, scoreb, negb);
  k_final<<<1, 128, 0, stream>>>(scoreb, negb, out);
}